// Round 5
// baseline (519.528 us; speedup 1.0000x reference)
//
#include <hip/hip_runtime.h>

// EmbeddingBagCollection: F tables [N,D] fp32, jagged sum-pool per bag.
// out[b, f*D + d] = sum_{i in [offs[f][b], offs[f][b+1])} tables[f][values[f][i]][d]
#define F_TABLES 8
#define B_BAGS   8192
#define N_ROWS   200000
#define D_DIM    64
#define T_IDX    163840

typedef float vfloat4 __attribute__((ext_vector_type(4)));  // native vec for nontemporal builtin

// One wave per bag. Per 64-index block: one coalesced index prefetch
// (lane i -> vals[rb+i]), then up to 16 4-row gather steps. Each step is
// wave-uniformly guarded (jj < steps, SGPR branch) so a 20-row bag issues
// 5 steps, not 16 — removes the 3.2x masked-slot VALU waste of R3 while
// keeping the identical memory access pattern (4 independent 256B row
// gathers in flight per step, up to 64 per wave).
__global__ __launch_bounds__(256, 8) void ebc_pool_kernel(
    const float* __restrict__ tables,
    const int*   __restrict__ values,
    const int*   __restrict__ offsets,
    float*       __restrict__ out)
{
    const int wave = blockIdx.x * (blockDim.x >> 6) + (threadIdx.x >> 6);
    const int lane = threadIdx.x & 63;
    const int g    = lane >> 4;        // row-group 0..3
    const int c    = lane & 15;        // float4 chunk within row

    const int f = wave >> 13;          // wave / B_BAGS
    const int b = wave & (B_BAGS - 1);

    const vfloat4* __restrict__ tab =
        (const vfloat4*)(tables + (size_t)f * N_ROWS * D_DIM);
    const int* __restrict__ vals = values + f * T_IDX;

    const int obase = f * (B_BAGS + 1) + b;
    const int s = offsets[obase];
    const int e = offsets[obase + 1];

    vfloat4 acc = (vfloat4){0.f, 0.f, 0.f, 0.f};

    for (int rb = s; rb < e; rb += 64) {
        const int cnt = min(64, e - rb);           // wave-uniform (SGPR)
        int myidx = 0;
        if (lane < cnt) myidx = vals[rb + lane];   // coalesced 256B idx fetch
        const int steps = (cnt + 3) >> 2;          // wave-uniform step count
        #pragma unroll
        for (int jj = 0; jj < 16; ++jj) {
            if (jj < steps) {                      // scalar branch, ~2 SALU when skipped
                const int pos = jj * 4 + g;
                const int idx = __shfl(myidx, pos, 64);
                if (pos < cnt) {                   // per-lane mask (boundary step only)
                    acc += tab[(size_t)idx * (D_DIM / 4) + c];
                }
            }
        }
    }

    // fold the 4 group-partials (lanes c, c+16, c+32, c+48 hold same dims)
    #pragma unroll
    for (int m = 16; m < 64; m <<= 1) {
        acc.x += __shfl_xor(acc.x, m, 64);
        acc.y += __shfl_xor(acc.y, m, 64);
        acc.z += __shfl_xor(acc.z, m, 64);
        acc.w += __shfl_xor(acc.w, m, 64);
    }

    if (lane < 16) {
        vfloat4* o = (vfloat4*)(out + (size_t)b * (F_TABLES * D_DIM) + f * D_DIM);
        __builtin_nontemporal_store(acc, o + c);   // keep L2/L3 for table rows
    }
}

extern "C" void kernel_launch(void* const* d_in, const int* in_sizes, int n_in,
                              void* d_out, int out_size, void* d_ws, size_t ws_size,
                              hipStream_t stream) {
    const float* tables  = (const float*)d_in[0];
    const int*   values  = (const int*)d_in[1];
    const int*   offsets = (const int*)d_in[2];
    float*       out     = (float*)d_out;

    // F*B = 65536 waves, 4 waves per 256-thread block -> 16384 blocks
    const int blocks = (F_TABLES * B_BAGS) / 4;
    hipLaunchKernelGGL(ebc_pool_kernel, dim3(blocks), dim3(256), 0, stream,
                       tables, values, offsets, out);
}